// Round 16
// baseline (195.424 us; speedup 1.0000x reference)
//
#include <hip/hip_runtime.h>

// ---------------------------------------------------------------------------
// RoPE GQA attention block, MI355X bf16-MFMA implementation (round 16).
// B=2 S=2048 D=2048 H=16 HKV=4 DH=128.  head h uses kv head h%4 (torch tile).
// Round 16: T1 XCD-aware block swizzle on gemm4p (each XCD gets 2 grid-rows ->
// B panels L2-resident) and flash (each XCD's 64 blocks share one (b,kv) K/V
// pair via chunked swizzle + 4x4 head transpose). Pure index permutations.
// ---------------------------------------------------------------------------

typedef __attribute__((ext_vector_type(8))) short  short8;
typedef __attribute__((ext_vector_type(8))) __bf16 bf16x8;
typedef __attribute__((ext_vector_type(4))) float  f32x4;

#define B_   2
#define S_   2048
#define D_   2048
#define H_   16
#define HKV_ 4
#define DH_  128
#define M_   4096  // B*S
#define NQKV 3072  // fused projection width: 2048 Q + 512 K + 512 V

static __device__ __forceinline__ ushort f2bf(float f) {
  __bf16 h = (__bf16)f;                      // native cvt (RNE)
  return __builtin_bit_cast(unsigned short, h);
}
static __device__ __forceinline__ float bf2f(ushort u) {
  union { unsigned u; float f; } v; v.u = ((unsigned)u) << 16;
  return v.f;
}
static __device__ __forceinline__ f32x4 mfma16(short8 a, short8 b, f32x4 c) {
  return __builtin_amdgcn_mfma_f32_16x16x32_bf16(
      __builtin_bit_cast(bf16x8, a), __builtin_bit_cast(bf16x8, b), c, 0, 0, 0);
}
// async global->LDS, 16B per lane; lds base must be wave-uniform.
static __device__ __forceinline__ void gload16(const ushort* g, ushort* l) {
  __builtin_amdgcn_global_load_lds(
      (const __attribute__((address_space(1))) unsigned int*)g,
      (__attribute__((address_space(3))) unsigned int*)l, 16, 0, 0);
}
template <int N>
static __device__ __forceinline__ void vmwait() {
  asm volatile("s_waitcnt vmcnt(%0)" :: "n"(N) : "memory");
}

// ---------------- prep: x cast || rope table || 4 weight transposes --------
// blocks: [0,8192) x-cast; [8192,8704) rope table; [8704,18944) transposes.
__global__ __launch_bounds__(256) void prep(const float* __restrict__ x,
                                            const float* __restrict__ Wq,
                                            const float* __restrict__ Wk,
                                            const float* __restrict__ Wv,
                                            const float* __restrict__ Wo,
                                            ushort* __restrict__ xb,
                                            ushort* __restrict__ Wqkvt,
                                            ushort* __restrict__ Wot,
                                            float2* __restrict__ tab) {
  __shared__ float tile[32][33];
  const int b = blockIdx.x, tid = threadIdx.x;
  if (b < 8192) {                       // x: f32 -> bf16, 4 elems/thread
    int i = b * 256 + tid;
    float4 v = ((const float4*)x)[i];
    ushort4 o;
    o.x = f2bf(v.x); o.y = f2bf(v.y); o.z = f2bf(v.z); o.w = f2bf(v.w);
    ((ushort4*)xb)[i] = o;
    return;
  }
  if (b < 8704) {                       // rope cos/sin table [S][64]
    int i = (b - 8704 + 512) * 256 + tid;
    int pos = i >> 6, f = i & 63;
    float freq = powf(10000.0f, -(float)f / 64.0f);
    float a = (float)pos * freq;
    tab[i] = make_float2(cosf(a), sinf(a));
    return;
  }
  // weight transpose+convert: W[R][C] f32 -> Wt[C][R] bf16
  int t = b - 8704;
  const float* src; ushort* dst; int R, C, bx, by;
  if (t < 4096)      { src = Wq; dst = Wqkvt;                        R = 2048; C = 2048; bx = t & 63; by = t >> 6; }
  else if (t < 5120) { t -= 4096; src = Wk; dst = Wqkvt + (size_t)2048 * 2048; R = 2048; C = 512;  bx = t & 15; by = t >> 4; }
  else if (t < 6144) { t -= 5120; src = Wv; dst = Wqkvt + (size_t)2560 * 2048; R = 2048; C = 512;  bx = t & 15; by = t >> 4; }
  else               { t -= 6144; src = Wo; dst = Wot;                R = 2048; C = 2048; bx = t & 63; by = t >> 6; }
  int c0 = bx * 32, r0 = by * 32;
  int tx = tid & 31, ty = tid >> 5;     // (32,8)
#pragma unroll
  for (int i = 0; i < 32; i += 8)
    tile[ty + i][tx] = src[(size_t)(r0 + ty + i) * C + c0 + tx];
  __syncthreads();
#pragma unroll
  for (int i = 0; i < 32; i += 8)
    dst[(size_t)(c0 + ty + i) * R + r0 + tx] = f2bf(tile[tx][ty + i]);
}

// ---------------- postqkv: RoPE(Q,K) 2x-vectorized || V transpose ----------
// blocks [0,10240): rope vec2 (Q: 8192 blocks, K: 2048 blocks).
// blocks [10240,12288): V transpose QKV[.,2560+kv*128+d] -> Vt[B,kv,128,S].
__global__ __launch_bounds__(256) void postqkv(ushort* __restrict__ qkv,
                                               const float2* __restrict__ tab,
                                               float qscale,
                                               ushort* __restrict__ Vt) {
  const int b = blockIdx.x, tid = threadIdx.x;
  if (b < 10240) {                      // RoPE, 2 pairs (4 ushorts) / thread
    int idx = b * 256 + tid;
    const int totq = M_ * 512;          // Q vec2 count
    ushort* t; int shift; float osc;
    if (idx < totq) { t = qkv; shift = 9; osc = qscale; }
    else { idx -= totq; t = qkv + 2048; shift = 7; osc = 1.0f; }
    int row = idx >> shift;
    int p   = idx & ((1 << shift) - 1);
    int head = p >> 5, fi2 = p & 31;    // fi2 = pair-pair index (fi = 2*fi2)
    int pos = row & (S_ - 1);
    float4 cs = ((const float4*)tab)[(pos << 5) + fi2];  // {cos,sin}x2
    size_t off = (size_t)row * NQKV + head * DH_ + 4 * fi2;
    ushort4 v = *(ushort4*)&t[off];
    float x0 = bf2f(v.x), x1 = bf2f(v.y), x2 = bf2f(v.z), x3 = bf2f(v.w);
    ushort4 o;
    o.x = f2bf((x0 * cs.x - x1 * cs.y) * osc);
    o.y = f2bf((x0 * cs.y + x1 * cs.x) * osc);
    o.z = f2bf((x2 * cs.z - x3 * cs.w) * osc);
    o.w = f2bf((x2 * cs.w + x3 * cs.z) * osc);
    *(ushort4*)&t[off] = o;
    return;
  }
  // V transpose: tvb -> (bx 0..3, by 0..63, bkv 0..7)
  __shared__ ushort tile[32][33];
  int tvb = b - 10240;
  int bx = tvb & 3, by = (tvb >> 2) & 63, bkv = tvb >> 8;
  const ushort* src = qkv + (size_t)(bkv >> 2) * S_ * NQKV + (bkv & 3) * DH_ + 2560;
  ushort* dst = Vt + (size_t)bkv * DH_ * S_;
  int d0 = bx * 32, s0 = by * 32;
  int tx = tid & 31, ty = tid >> 5;     // (32,8)
#pragma unroll
  for (int i = 0; i < 32; i += 8)
    tile[ty + i][tx] = src[(size_t)(s0 + ty + i) * NQKV + d0 + tx];
  __syncthreads();
#pragma unroll
  for (int i = 0; i < 32; i += 8)
    dst[(size_t)(d0 + ty + i) * S_ + s0 + tx] = tile[tx][ty + i];
}

// ---------------- gemm4p: C[M,N] = A[M,K] * Bt[N,K]^T ----------------------
// BM=256, BN=192/128, BK=64. 8 waves as 4M x 2N; per-wave 64 x BN/2.
// 2 phases (J=0,1) per K-tile, dbuf LDS, counted vmcnt (never 0 in loop).
// T1: chunked XCD swizzle — XCD j owns grid-rows {2j,2j+1} (B panels stay
// L2-resident per XCD).
template <int BN, int NF, typename OutT>
__global__ __launch_bounds__(512, 1) void gemm4p(const ushort* __restrict__ A,
                                                 const ushort* __restrict__ Bt,
                                                 OutT* __restrict__ C,
                                                 int M, int N, int K) {
  __shared__ ushort As[2][256 * 64];
  __shared__ ushort Bs[2][BN * 64];
  constexpr int NBR = BN / 64;             // B gload rounds per K-tile
  const int tid = threadIdx.x;
  const int lane = tid & 63, w = tid >> 6;
  const int l16 = lane & 15, l4 = lane >> 4;
  const int wm = (w >> 1) * 64, wn = (w & 1) * (BN / 2);

  // XCD-chunked bijective swizzle (nwg = 16*gridDim.y, divisible by 8)
  const int nx = gridDim.x;
  const int nwg = nx * gridDim.y;
  const int dsp = blockIdx.y * nx + blockIdx.x;
  const int lin = (dsp & 7) * (nwg >> 3) + (dsp >> 3);
  const int bm = (lin % nx) * 256, bn = (lin / nx) * BN;

  const int swz = l16 & 7;                 // ds_read colblk swizzle

  const ushort* gA = A  + (size_t)bm * K;
  const ushort* gB = Bt + (size_t)bn * K;
  const int srow = tid >> 3;               // 0..63 within a round
  const int scb  = tid & 7;                // colblk 0..7
  const int sswz = srow & 7;

  auto stageA = [&](int t, int s, int g) {
    int row = g * 64 + srow;
    gload16(gA + (size_t)row * K + t * 64 + ((scb ^ sswz) * 8),
            &As[s][(g * 64 + w * 8) * 64]);
  };
  auto stageA4 = [&](int t, int s) {
#pragma unroll
    for (int g = 0; g < 4; ++g) stageA(t, s, g);
  };
  auto stageBall = [&](int t, int s) {
#pragma unroll
    for (int g = 0; g < NBR; ++g) {
      int row = g * 64 + srow;
      gload16(gB + (size_t)row * K + t * 64 + ((scb ^ sswz) * 8),
              &Bs[s][(g * 64 + w * 8) * 64]);
    }
  };

  f32x4 acc[4][NF] = {};
  short8 bfr[NF][2];
  const int NT  = K / 64;
  const int NIT = K / 128;

  // ---- prologue: B(0), A(0), B(1); retire tile0 ----
  stageBall(0, 0);
  stageA4(0, 0);
  stageBall(1, 1);
  vmwait<NBR>();
  __builtin_amdgcn_s_barrier();
  __builtin_amdgcn_sched_barrier(0);

#define GPHASE(S, J, ISSUES, VMW)                                             \
  {                                                                           \
    short8 afr[2][2];                                                         \
    _Pragma("unroll")                                                         \
    for (int mf = 0; mf < 2; ++mf) {                                          \
      _Pragma("unroll")                                                       \
      for (int kk = 0; kk < 2; ++kk) {                                        \
        int row = wm + (J) * 32 + mf * 16 + l16;                              \
        afr[mf][kk] =                                                         \
            *(const short8*)&As[S][row * 64 + (((kk * 4 + l4) ^ swz) * 8)];   \
      }                                                                       \
    }                                                                         \
    if ((J) == 0) {                                                           \
      _Pragma("unroll")                                                       \
      for (int nf = 0; nf < NF; ++nf) {                                       \
        _Pragma("unroll")                                                     \
        for (int kk = 0; kk < 2; ++kk) {                                      \
          int row = wn + nf * 16 + l16;                                       \
          bfr[nf][kk] =                                                       \
              *(const short8*)&Bs[S][row * 64 + (((kk * 4 + l4) ^ swz) * 8)]; \
        }                                                                     \
      }                                                                       \
    }                                                                         \
    ISSUES;                                                                   \
    __builtin_amdgcn_s_barrier();                                             \
    asm volatile("s_waitcnt lgkmcnt(0)" ::: "memory");                        \
    __builtin_amdgcn_sched_barrier(0);                                        \
    __builtin_amdgcn_s_setprio(1);                                            \
    _Pragma("unroll")                                                         \
    for (int kk = 0; kk < 2; ++kk) {                                          \
      _Pragma("unroll")                                                       \
      for (int mf = 0; mf < 2; ++mf) {                                        \
        _Pragma("unroll")                                                     \
        for (int nf = 0; nf < NF; ++nf)                                       \
          acc[(J) * 2 + mf][nf] =                                             \
              mfma16(afr[mf][kk], bfr[nf][kk], acc[(J) * 2 + mf][nf]);        \
      }                                                                       \
    }                                                                         \
    __builtin_amdgcn_s_setprio(0);                                            \
    VMW;                                                                      \
    __builtin_amdgcn_s_barrier();                                             \
    __builtin_amdgcn_sched_barrier(0);                                        \
  }

  for (int i = 0; i < NIT; ++i) {
    const int tb = 2 * i + 1;
    const int t2 = (2 * i + 2 < NT) ? 2 * i + 2 : NT - 1;   // clamped tail
    const int t3 = (2 * i + 3 < NT) ? 2 * i + 3 : NT - 1;
    GPHASE(0, 0, (stageA4(tb, 1)),  (void)0)         // tile a=2i, rows 0-31
    GPHASE(0, 1, (stageBall(t2, 0)), vmwait<NBR>())  // tile a, rows 32-63
    GPHASE(1, 0, (stageA4(t2, 0)),  (void)0)         // tile b=2i+1
    GPHASE(1, 1, (stageBall(t3, 1)), vmwait<NBR>())
  }
#undef GPHASE

  asm volatile("s_waitcnt vmcnt(0)" ::: "memory");  // drain LDS DMA pre-exit

  // epilogue: C/D layout col=lane&15, row=(lane>>4)*4+reg
#pragma unroll
  for (int mi = 0; mi < 4; ++mi) {
#pragma unroll
    for (int nf = 0; nf < NF; ++nf) {
#pragma unroll
      for (int r = 0; r < 4; ++r) {
        size_t row = bm + wm + (mi >> 1) * 32 + (mi & 1) * 16 + l4 * 4 + r;
        size_t col = bn + wn + nf * 16 + l16;
        if constexpr (sizeof(OutT) == 2)
          C[row * N + col] = f2bf(acc[mi][nf][r]);
        else
          C[row * N + col] = acc[mi][nf][r];
      }
    }
  }
}

// ---------------- flash attention (round-14 compute, XCD-grouped grid) -----
// grid (16, 32) = 512 blocks; chunked XCD swizzle + 4x4 head transpose so
// each XCD's 64 blocks share one (b, kv) K/V pair (1 MB, L2-resident).
// 4 waves/block, wave owns 32 q rows (2 q-groups of 16); KBLK=64, dbuf LDS,
// counted-vmcnt wait discipline (no vmcnt(0) in loop).
__global__ __launch_bounds__(256, 2) void flash_attn(const ushort* __restrict__ Qp,
                                                     const ushort* __restrict__ Kp,
                                                     const ushort* __restrict__ Vt,
                                                     ushort* __restrict__ Oa) {
  __shared__ ushort Ks[2][64 * 128];    // [key][d], swizzle (r&3)|((r>>3)&1)<<2
  __shared__ ushort Vs[2][128 * 64];    // [d][key], swizzle d&7
  const int tid = threadIdx.x;
  const int lane = tid & 63, wave = tid >> 6;
  const int l16 = lane & 15, l4 = lane >> 4;

  // XCD-chunked remap: XCD j gets lin in [64j, 64j+64) = 4 bh-slots x 16 xq;
  // head transpose makes those 4 slots share (b, kv).
  const int dsp = blockIdx.y * 16 + blockIdx.x;      // [0,512)
  const int lin = (dsp & 7) * 64 + (dsp >> 3);
  const int xq = lin & 15, bhs = lin >> 4;           // bhs in [0,32)
  const int b = bhs >> 4, j = bhs & 15;
  const int h = ((j & 3) << 2) | (j >> 2);           // 4x4 transpose
  const int kv = h & 3;
  const int q0 = xq * 128 + wave * 32;

  short8 qf[2][4];
#pragma unroll
  for (int qg = 0; qg < 2; ++qg) {
    const ushort* qrow =
        Qp + ((size_t)(b * S_ + q0 + qg * 16 + l16)) * NQKV + h * DH_ + l4 * 8;
#pragma unroll
    for (int kk = 0; kk < 4; ++kk) qf[qg][kk] = *(const short8*)(qrow + kk * 32);
  }

  const ushort* kbase = Kp + (size_t)(b * S_) * NQKV + kv * DH_;
  const ushort* vbase = Vt + (size_t)(b * HKV_ + kv) * DH_ * S_;

  float mreg[2] = {0.f, 0.f};           // exp2-domain scores stay small
  f32x4 o[2][8] = {};
  f32x4 ol[2] = {};                     // P row-sums (ones-column MFMA)
  short8 onesf;
#pragma unroll
  for (int jj = 0; jj < 8; ++jj) onesf[jj] = (short)0x3F80;  // bf16 1.0

  const int kswz = (l16 & 3) | (((l16 >> 2) & 1) << 2);
  const int vswz = l16 & 7;

  const int krT = wave * 16 + (lane >> 4);
  const int kcT = lane & 15;
  const int vrT = wave * 32 + (lane >> 3);
  const int vcT = lane & 7;

  auto stage = [&](int t, int buf) {    // 8 gload16 per thread
#pragma unroll
    for (int i = 0; i < 4; ++i) {
      int r = krT + i * 4;
      int swzk = (r & 3) | (((r >> 3) & 1) << 2);
      gload16(kbase + (size_t)(t * 64 + r) * NQKV + ((kcT ^ swzk) * 8),
              &Ks[buf][(wave * 16 + i * 4) * 128]);
      int d = vrT + i * 8;
      gload16(vbase + (size_t)d * S_ + t * 64 + ((vcT ^ (d & 7)) * 8),
              &Vs[buf][(wave * 32 + i * 8) * 64]);
    }
  };

  const int NT = S_ / 64;
  vmwait<0>();                          // qf retired; clean vm ledger
  stage(0, 0);
  stage(1, 1);
  vmwait<8>();                          // tile0's 8 retired; tile1 in flight
  __builtin_amdgcn_s_barrier();
  __builtin_amdgcn_sched_barrier(0);

  for (int t = 0; t < NT; ++t) {
    const int cur = t & 1;

    // ---- QK^T (swapped, interleaved keys), K-fragments shared by 2 qg ----
    f32x4 s[2][4] = {};
    __builtin_amdgcn_s_setprio(1);
#pragma unroll
    for (int c = 0; c < 4; ++c) {
      const int krow = 32 * (c >> 1) + 8 * (l16 >> 2) + 4 * (c & 1) + (l16 & 3);
#pragma unroll
      for (int kk = 0; kk < 4; ++kk) {
        short8 kf = *(const short8*)&Ks[cur][krow * 128 + (((kk * 4 + l4) ^ kswz) * 8)];
        s[0][c] = mfma16(kf, qf[0][kk], s[0][c]);
        s[1][c] = mfma16(kf, qf[1][kk], s[1][c]);
      }
    }
    __builtin_amdgcn_s_setprio(0);

    // lane-local max per q-group (cross-lane reduce only if rescale needed)
    float lmax[2];
#pragma unroll
    for (int qg = 0; qg < 2; ++qg) {
      float a = fmaxf(fmaxf(s[qg][0][0], s[qg][0][1]), fmaxf(s[qg][0][2], s[qg][0][3]));
#pragma unroll
      for (int c = 1; c < 4; ++c) {
        a = fmaxf(a, fmaxf(fmaxf(s[qg][c][0], s[qg][c][1]),
                           fmaxf(s[qg][c][2], s[qg][c][3])));
      }
      lmax[qg] = a;
    }

    bool ok = (lmax[0] - mreg[0] <= 8.0f) && (lmax[1] - mreg[1] <= 8.0f);
    if (!__all(ok)) {                   // defer-max (T13): rare rescale
#pragma unroll
      for (int qg = 0; qg < 2; ++qg) {
        float a = fmaxf(lmax[qg], __shfl_xor(lmax[qg], 16));
        float tmax = fmaxf(a, __shfl_xor(a, 32));
        float mn = fmaxf(mreg[qg], tmax);
        float alpha = __builtin_amdgcn_exp2f(mreg[qg] - mn);
        mreg[qg] = mn;
        float af[4];
#pragma unroll
        for (int r = 0; r < 4; ++r)
          af[r] = __shfl(alpha, (lane & 48) + l4 * 4 + r);
#pragma unroll
        for (int g = 0; g < 8; ++g)
#pragma unroll
          for (int r = 0; r < 4; ++r) o[qg][g][r] *= af[r];
#pragma unroll
        for (int r = 0; r < 4; ++r) ol[qg][r] *= af[r];
      }
    }

    // ---- per ks-slice: softmax-finish then PV (MFMA||VALU overlap) ----
    short8 pa[2];
#pragma unroll
    for (int ks = 0; ks < 2; ++ks) {
#pragma unroll
      for (int qg = 0; qg < 2; ++qg) {
        short8 pk;
#pragma unroll
        for (int jj = 0; jj < 8; ++jj) {
          float p = __builtin_amdgcn_exp2f(s[qg][2 * ks + (jj >> 2)][jj & 3] - mreg[qg]);
          pk[jj] = (short)f2bf(p);
        }
        pa[qg] = pk;
      }
      __builtin_amdgcn_s_setprio(1);
#pragma unroll
      for (int g = 0; g < 8; ++g) {
        const int d = g * 16 + l16;
        short8 vf = *(const short8*)&Vs[cur][d * 64 + (((ks * 4 + l4) ^ vswz) * 8)];
        o[0][g] = mfma16(pa[0], vf, o[0][g]);
        o[1][g] = mfma16(pa[1], vf, o[1][g]);
      }
      ol[0] = mfma16(pa[0], onesf, ol[0]);   // row-sum on the matrix pipe
      ol[1] = mfma16(pa[1], onesf, ol[1]);
      __builtin_amdgcn_s_setprio(0);
    }

    // ---- counted-vmcnt pipeline epilogue of iteration t ----
    __builtin_amdgcn_s_barrier();       // all waves done reading buf[cur]
    __builtin_amdgcn_sched_barrier(0);
    if (t + 2 < NT) {
      stage(t + 2, cur);                // refill freed buffer (async)
      vmwait<8>();                      // retire t+1's 8; t+2 stays in flight
    } else if (t + 1 < NT) {
      vmwait<0>();                      // last prefetch: drain t+1
    }
    if (t + 1 < NT) {
      __builtin_amdgcn_s_barrier();     // publish buf[cur^1] = tile t+1
      __builtin_amdgcn_sched_barrier(0);
    }
  }

  // epilogue: O rows are q = qg*16 + l4*4 + r; 1/l available in-lane via ol
#pragma unroll
  for (int qg = 0; qg < 2; ++qg) {
    float invq[4];
#pragma unroll
    for (int r = 0; r < 4; ++r) invq[r] = 1.0f / ol[qg][r];
    ushort* op = Oa + (size_t)(b * S_ + q0 + qg * 16) * D_ + h * DH_;
#pragma unroll
    for (int g = 0; g < 8; ++g)
#pragma unroll
      for (int r = 0; r < 4; ++r)
        op[(size_t)(l4 * 4 + r) * D_ + g * 16 + l16] = f2bf(o[qg][g][r] * invq[r]);
  }
}

// ---------------------------------------------------------------------------
extern "C" void kernel_launch(void* const* d_in, const int* in_sizes, int n_in,
                              void* d_out, int out_size, void* d_ws, size_t ws_size,
                              hipStream_t stream) {
  (void)in_sizes; (void)n_in; (void)out_size; (void)ws_size;
  const float* x  = (const float*)d_in[0];
  const float* Wq = (const float*)d_in[1];
  const float* Wk = (const float*)d_in[2];
  const float* Wv = (const float*)d_in[3];
  const float* Wo = (const float*)d_in[4];
  float* out = (float*)d_out;

  size_t off = 0;
  auto carve = [&](size_t bytes) -> void* {
    void* p = (char*)d_ws + off;
    off += (bytes + 255) & ~(size_t)255;
    return p;
  };
  ushort* xb    = (ushort*)carve((size_t)M_ * D_ * 2);
  ushort* Wqkvt = (ushort*)carve((size_t)NQKV * D_ * 2);   // [3072][2048]
  ushort* Wot   = (ushort*)carve((size_t)D_ * D_ * 2);
  ushort* QKV   = (ushort*)carve((size_t)M_ * NQKV * 2);   // [4096][3072]
  ushort* Vt    = (ushort*)carve((size_t)M_ * 512 * 2);
  ushort* attn  = (ushort*)carve((size_t)M_ * D_ * 2);
  float2* tab   = (float2*)carve((size_t)S_ * 64 * sizeof(float2));

  // 1. prep: x cast + rope table + all weight transposes (one launch)
  prep<<<18944, 256, 0, stream>>>(x, Wq, Wk, Wv, Wo, xb, Wqkvt, Wot, tab);

  // 2. fused QKV projection: [4096,2048] x [3072,2048]^T -> [4096,3072]
  gemm4p<192, 6, ushort><<<dim3(16, 16), 512, 0, stream>>>(xb, Wqkvt, QKV, M_, NQKV, 2048);

  // 3. RoPE Q+K (vec2, exp2-domain Q scale) + V transpose, one launch
  const float qscale = 0.08838834764831845f * 1.4426950408889634f;
  postqkv<<<12288, 256, 0, stream>>>(QKV, tab, qscale, Vt);

  // 4. attention
  flash_attn<<<dim3(16, 32), 256, 0, stream>>>(QKV, QKV + 2048, Vt, attn);

  // 5. output projection (f32 out)
  gemm4p<128, 4, float><<<dim3(16, 16), 512, 0, stream>>>(attn, Wot, out, M_, 2048, 2048);
}

// Round 17
// 194.826 us; speedup vs baseline: 1.0031x; 1.0031x over previous
//
#include <hip/hip_runtime.h>

// ---------------------------------------------------------------------------
// RoPE GQA attention block, MI355X bf16-MFMA implementation (round 17).
// B=2 S=2048 D=2048 H=16 HKV=4 DH=128.  head h uses kv head h%4 (torch tile).
// Round 17: flash K-loop unrolled by 2 so the LDS buffer index is a literal
// -> all swizzled ds_read addresses fold to loop-invariant base + immediate
// offset (kills per-tile VALU address recomputation). Everything else is the
// round-16 best (XCD-grouped flash + gemm, counted vmcnt, fused prep/postqkv).
// ---------------------------------------------------------------------------

typedef __attribute__((ext_vector_type(8))) short  short8;
typedef __attribute__((ext_vector_type(8))) __bf16 bf16x8;
typedef __attribute__((ext_vector_type(4))) float  f32x4;

#define B_   2
#define S_   2048
#define D_   2048
#define H_   16
#define HKV_ 4
#define DH_  128
#define M_   4096  // B*S
#define NQKV 3072  // fused projection width: 2048 Q + 512 K + 512 V

static __device__ __forceinline__ ushort f2bf(float f) {
  __bf16 h = (__bf16)f;                      // native cvt (RNE)
  return __builtin_bit_cast(unsigned short, h);
}
static __device__ __forceinline__ float bf2f(ushort u) {
  union { unsigned u; float f; } v; v.u = ((unsigned)u) << 16;
  return v.f;
}
static __device__ __forceinline__ f32x4 mfma16(short8 a, short8 b, f32x4 c) {
  return __builtin_amdgcn_mfma_f32_16x16x32_bf16(
      __builtin_bit_cast(bf16x8, a), __builtin_bit_cast(bf16x8, b), c, 0, 0, 0);
}
// async global->LDS, 16B per lane; lds base must be wave-uniform.
static __device__ __forceinline__ void gload16(const ushort* g, ushort* l) {
  __builtin_amdgcn_global_load_lds(
      (const __attribute__((address_space(1))) unsigned int*)g,
      (__attribute__((address_space(3))) unsigned int*)l, 16, 0, 0);
}
template <int N>
static __device__ __forceinline__ void vmwait() {
  asm volatile("s_waitcnt vmcnt(%0)" :: "n"(N) : "memory");
}

// ---------------- prep: x cast || rope table || 4 weight transposes --------
// blocks: [0,8192) x-cast; [8192,8704) rope table; [8704,18944) transposes.
__global__ __launch_bounds__(256) void prep(const float* __restrict__ x,
                                            const float* __restrict__ Wq,
                                            const float* __restrict__ Wk,
                                            const float* __restrict__ Wv,
                                            const float* __restrict__ Wo,
                                            ushort* __restrict__ xb,
                                            ushort* __restrict__ Wqkvt,
                                            ushort* __restrict__ Wot,
                                            float2* __restrict__ tab) {
  __shared__ float tile[32][33];
  const int b = blockIdx.x, tid = threadIdx.x;
  if (b < 8192) {                       // x: f32 -> bf16, 4 elems/thread
    int i = b * 256 + tid;
    float4 v = ((const float4*)x)[i];
    ushort4 o;
    o.x = f2bf(v.x); o.y = f2bf(v.y); o.z = f2bf(v.z); o.w = f2bf(v.w);
    ((ushort4*)xb)[i] = o;
    return;
  }
  if (b < 8704) {                       // rope cos/sin table [S][64]
    int i = (b - 8704 + 512) * 256 + tid;
    int pos = i >> 6, f = i & 63;
    float freq = powf(10000.0f, -(float)f / 64.0f);
    float a = (float)pos * freq;
    tab[i] = make_float2(cosf(a), sinf(a));
    return;
  }
  // weight transpose+convert: W[R][C] f32 -> Wt[C][R] bf16
  int t = b - 8704;
  const float* src; ushort* dst; int R, C, bx, by;
  if (t < 4096)      { src = Wq; dst = Wqkvt;                        R = 2048; C = 2048; bx = t & 63; by = t >> 6; }
  else if (t < 5120) { t -= 4096; src = Wk; dst = Wqkvt + (size_t)2048 * 2048; R = 2048; C = 512;  bx = t & 15; by = t >> 4; }
  else if (t < 6144) { t -= 5120; src = Wv; dst = Wqkvt + (size_t)2560 * 2048; R = 2048; C = 512;  bx = t & 15; by = t >> 4; }
  else               { t -= 6144; src = Wo; dst = Wot;                R = 2048; C = 2048; bx = t & 63; by = t >> 6; }
  int c0 = bx * 32, r0 = by * 32;
  int tx = tid & 31, ty = tid >> 5;     // (32,8)
#pragma unroll
  for (int i = 0; i < 32; i += 8)
    tile[ty + i][tx] = src[(size_t)(r0 + ty + i) * C + c0 + tx];
  __syncthreads();
#pragma unroll
  for (int i = 0; i < 32; i += 8)
    dst[(size_t)(c0 + ty + i) * R + r0 + tx] = f2bf(tile[tx][ty + i]);
}

// ---------------- postqkv: RoPE(Q,K) 2x-vectorized || V transpose ----------
__global__ __launch_bounds__(256) void postqkv(ushort* __restrict__ qkv,
                                               const float2* __restrict__ tab,
                                               float qscale,
                                               ushort* __restrict__ Vt) {
  const int b = blockIdx.x, tid = threadIdx.x;
  if (b < 10240) {                      // RoPE, 2 pairs (4 ushorts) / thread
    int idx = b * 256 + tid;
    const int totq = M_ * 512;          // Q vec2 count
    ushort* t; int shift; float osc;
    if (idx < totq) { t = qkv; shift = 9; osc = qscale; }
    else { idx -= totq; t = qkv + 2048; shift = 7; osc = 1.0f; }
    int row = idx >> shift;
    int p   = idx & ((1 << shift) - 1);
    int head = p >> 5, fi2 = p & 31;
    int pos = row & (S_ - 1);
    float4 cs = ((const float4*)tab)[(pos << 5) + fi2];  // {cos,sin}x2
    size_t off = (size_t)row * NQKV + head * DH_ + 4 * fi2;
    ushort4 v = *(ushort4*)&t[off];
    float x0 = bf2f(v.x), x1 = bf2f(v.y), x2 = bf2f(v.z), x3 = bf2f(v.w);
    ushort4 o;
    o.x = f2bf((x0 * cs.x - x1 * cs.y) * osc);
    o.y = f2bf((x0 * cs.y + x1 * cs.x) * osc);
    o.z = f2bf((x2 * cs.z - x3 * cs.w) * osc);
    o.w = f2bf((x2 * cs.w + x3 * cs.z) * osc);
    *(ushort4*)&t[off] = o;
    return;
  }
  // V transpose: tvb -> (bx 0..3, by 0..63, bkv 0..7)
  __shared__ ushort tile[32][33];
  int tvb = b - 10240;
  int bx = tvb & 3, by = (tvb >> 2) & 63, bkv = tvb >> 8;
  const ushort* src = qkv + (size_t)(bkv >> 2) * S_ * NQKV + (bkv & 3) * DH_ + 2560;
  ushort* dst = Vt + (size_t)bkv * DH_ * S_;
  int d0 = bx * 32, s0 = by * 32;
  int tx = tid & 31, ty = tid >> 5;     // (32,8)
#pragma unroll
  for (int i = 0; i < 32; i += 8)
    tile[ty + i][tx] = src[(size_t)(s0 + ty + i) * NQKV + d0 + tx];
  __syncthreads();
#pragma unroll
  for (int i = 0; i < 32; i += 8)
    dst[(size_t)(d0 + ty + i) * S_ + s0 + tx] = tile[tx][ty + i];
}

// ---------------- gemm4p: C[M,N] = A[M,K] * Bt[N,K]^T ----------------------
// BM=256, BN=192/128, BK=64. 8 waves as 4M x 2N; per-wave 64 x BN/2.
// 2 phases (J=0,1) per K-tile, dbuf LDS, counted vmcnt (never 0 in loop).
// T1: chunked XCD swizzle.
template <int BN, int NF, typename OutT>
__global__ __launch_bounds__(512, 1) void gemm4p(const ushort* __restrict__ A,
                                                 const ushort* __restrict__ Bt,
                                                 OutT* __restrict__ C,
                                                 int M, int N, int K) {
  __shared__ ushort As[2][256 * 64];
  __shared__ ushort Bs[2][BN * 64];
  constexpr int NBR = BN / 64;             // B gload rounds per K-tile
  const int tid = threadIdx.x;
  const int lane = tid & 63, w = tid >> 6;
  const int l16 = lane & 15, l4 = lane >> 4;
  const int wm = (w >> 1) * 64, wn = (w & 1) * (BN / 2);

  // XCD-chunked bijective swizzle (nwg divisible by 8)
  const int nx = gridDim.x;
  const int nwg = nx * gridDim.y;
  const int dsp = blockIdx.y * nx + blockIdx.x;
  const int lin = (dsp & 7) * (nwg >> 3) + (dsp >> 3);
  const int bm = (lin % nx) * 256, bn = (lin / nx) * BN;

  const int swz = l16 & 7;                 // ds_read colblk swizzle

  const ushort* gA = A  + (size_t)bm * K;
  const ushort* gB = Bt + (size_t)bn * K;
  const int srow = tid >> 3;               // 0..63 within a round
  const int scb  = tid & 7;                // colblk 0..7
  const int sswz = srow & 7;

  auto stageA = [&](int t, int s, int g) {
    int row = g * 64 + srow;
    gload16(gA + (size_t)row * K + t * 64 + ((scb ^ sswz) * 8),
            &As[s][(g * 64 + w * 8) * 64]);
  };
  auto stageA4 = [&](int t, int s) {
#pragma unroll
    for (int g = 0; g < 4; ++g) stageA(t, s, g);
  };
  auto stageBall = [&](int t, int s) {
#pragma unroll
    for (int g = 0; g < NBR; ++g) {
      int row = g * 64 + srow;
      gload16(gB + (size_t)row * K + t * 64 + ((scb ^ sswz) * 8),
              &Bs[s][(g * 64 + w * 8) * 64]);
    }
  };

  f32x4 acc[4][NF] = {};
  short8 bfr[NF][2];
  const int NT  = K / 64;
  const int NIT = K / 128;

  // ---- prologue: B(0), A(0), B(1); retire tile0 ----
  stageBall(0, 0);
  stageA4(0, 0);
  stageBall(1, 1);
  vmwait<NBR>();
  __builtin_amdgcn_s_barrier();
  __builtin_amdgcn_sched_barrier(0);

#define GPHASE(S, J, ISSUES, VMW)                                             \
  {                                                                           \
    short8 afr[2][2];                                                         \
    _Pragma("unroll")                                                         \
    for (int mf = 0; mf < 2; ++mf) {                                          \
      _Pragma("unroll")                                                       \
      for (int kk = 0; kk < 2; ++kk) {                                        \
        int row = wm + (J) * 32 + mf * 16 + l16;                              \
        afr[mf][kk] =                                                         \
            *(const short8*)&As[S][row * 64 + (((kk * 4 + l4) ^ swz) * 8)];   \
      }                                                                       \
    }                                                                         \
    if ((J) == 0) {                                                           \
      _Pragma("unroll")                                                       \
      for (int nf = 0; nf < NF; ++nf) {                                       \
        _Pragma("unroll")                                                     \
        for (int kk = 0; kk < 2; ++kk) {                                      \
          int row = wn + nf * 16 + l16;                                       \
          bfr[nf][kk] =                                                       \
              *(const short8*)&Bs[S][row * 64 + (((kk * 4 + l4) ^ swz) * 8)]; \
        }                                                                     \
      }                                                                       \
    }                                                                         \
    ISSUES;                                                                   \
    __builtin_amdgcn_s_barrier();                                             \
    asm volatile("s_waitcnt lgkmcnt(0)" ::: "memory");                        \
    __builtin_amdgcn_sched_barrier(0);                                        \
    __builtin_amdgcn_s_setprio(1);                                            \
    _Pragma("unroll")                                                         \
    for (int kk = 0; kk < 2; ++kk) {                                          \
      _Pragma("unroll")                                                       \
      for (int mf = 0; mf < 2; ++mf) {                                        \
        _Pragma("unroll")                                                     \
        for (int nf = 0; nf < NF; ++nf)                                       \
          acc[(J) * 2 + mf][nf] =                                             \
              mfma16(afr[mf][kk], bfr[nf][kk], acc[(J) * 2 + mf][nf]);        \
      }                                                                       \
    }                                                                         \
    __builtin_amdgcn_s_setprio(0);                                            \
    VMW;                                                                      \
    __builtin_amdgcn_s_barrier();                                             \
    __builtin_amdgcn_sched_barrier(0);                                        \
  }

  for (int i = 0; i < NIT; ++i) {
    const int tb = 2 * i + 1;
    const int t2 = (2 * i + 2 < NT) ? 2 * i + 2 : NT - 1;   // clamped tail
    const int t3 = (2 * i + 3 < NT) ? 2 * i + 3 : NT - 1;
    GPHASE(0, 0, (stageA4(tb, 1)),  (void)0)         // tile a=2i, rows 0-31
    GPHASE(0, 1, (stageBall(t2, 0)), vmwait<NBR>())  // tile a, rows 32-63
    GPHASE(1, 0, (stageA4(t2, 0)),  (void)0)         // tile b=2i+1
    GPHASE(1, 1, (stageBall(t3, 1)), vmwait<NBR>())
  }
#undef GPHASE

  asm volatile("s_waitcnt vmcnt(0)" ::: "memory");  // drain LDS DMA pre-exit

  // epilogue: C/D layout col=lane&15, row=(lane>>4)*4+reg
#pragma unroll
  for (int mi = 0; mi < 4; ++mi) {
#pragma unroll
    for (int nf = 0; nf < NF; ++nf) {
#pragma unroll
      for (int r = 0; r < 4; ++r) {
        size_t row = bm + wm + (mi >> 1) * 32 + (mi & 1) * 16 + l4 * 4 + r;
        size_t col = bn + wn + nf * 16 + l16;
        if constexpr (sizeof(OutT) == 2)
          C[row * N + col] = f2bf(acc[mi][nf][r]);
        else
          C[row * N + col] = acc[mi][nf][r];
      }
    }
  }
}

// ---------------- flash attention (round 17) -------------------------------
// Round-16 structure (XCD-grouped grid, KBLK=64, dbuf, counted vmcnt), with
// the K-loop unrolled by 2 so the LDS buffer index is a compile-time literal
// (ds_read addresses fold to base + immediate offset; VALU addressing cut).
__global__ __launch_bounds__(256, 2) void flash_attn(const ushort* __restrict__ Qp,
                                                     const ushort* __restrict__ Kp,
                                                     const ushort* __restrict__ Vt,
                                                     ushort* __restrict__ Oa) {
  __shared__ ushort Ks[2][64 * 128];    // [key][d], swizzle (r&3)|((r>>3)&1)<<2
  __shared__ ushort Vs[2][128 * 64];    // [d][key], swizzle d&7
  const int tid = threadIdx.x;
  const int lane = tid & 63, wave = tid >> 6;
  const int l16 = lane & 15, l4 = lane >> 4;

  // XCD-chunked remap: XCD j gets lin in [64j, 64j+64) = 4 bh-slots x 16 xq;
  // head transpose makes those 4 slots share (b, kv).
  const int dsp = blockIdx.y * 16 + blockIdx.x;      // [0,512)
  const int lin = (dsp & 7) * 64 + (dsp >> 3);
  const int xq = lin & 15, bhs = lin >> 4;           // bhs in [0,32)
  const int b = bhs >> 4, j = bhs & 15;
  const int h = ((j & 3) << 2) | (j >> 2);           // 4x4 transpose
  const int kv = h & 3;
  const int q0 = xq * 128 + wave * 32;

  short8 qf[2][4];
#pragma unroll
  for (int qg = 0; qg < 2; ++qg) {
    const ushort* qrow =
        Qp + ((size_t)(b * S_ + q0 + qg * 16 + l16)) * NQKV + h * DH_ + l4 * 8;
#pragma unroll
    for (int kk = 0; kk < 4; ++kk) qf[qg][kk] = *(const short8*)(qrow + kk * 32);
  }

  const ushort* kbase = Kp + (size_t)(b * S_) * NQKV + kv * DH_;
  const ushort* vbase = Vt + (size_t)(b * HKV_ + kv) * DH_ * S_;

  float mreg[2] = {0.f, 0.f};           // exp2-domain scores stay small
  f32x4 o[2][8] = {};
  f32x4 ol[2] = {};                     // P row-sums (ones-column MFMA)
  short8 onesf;
#pragma unroll
  for (int jj = 0; jj < 8; ++jj) onesf[jj] = (short)0x3F80;  // bf16 1.0

  const int kswz = (l16 & 3) | (((l16 >> 2) & 1) << 2);
  const int vswz = l16 & 7;

  const int krT = wave * 16 + (lane >> 4);
  const int kcT = lane & 15;
  const int vrT = wave * 32 + (lane >> 3);
  const int vcT = lane & 7;

  auto stage = [&](int t, int buf) {    // 8 gload16 per thread
#pragma unroll
    for (int i = 0; i < 4; ++i) {
      int r = krT + i * 4;
      int swzk = (r & 3) | (((r >> 3) & 1) << 2);
      gload16(kbase + (size_t)(t * 64 + r) * NQKV + ((kcT ^ swzk) * 8),
              &Ks[buf][(wave * 16 + i * 4) * 128]);
      int d = vrT + i * 8;
      gload16(vbase + (size_t)d * S_ + t * 64 + ((vcT ^ (d & 7)) * 8),
              &Vs[buf][(wave * 32 + i * 8) * 64]);
    }
  };

  const int NT = S_ / 64;
  vmwait<0>();                          // qf retired; clean vm ledger
  stage(0, 0);
  stage(1, 1);
  vmwait<8>();                          // tile0's 8 retired; tile1 in flight
  __builtin_amdgcn_s_barrier();
  __builtin_amdgcn_sched_barrier(0);

// One tile body with compile-time buffer index CUR, runtime tile index T.
#define FBODY(CUR, T)                                                         \
  {                                                                           \
    f32x4 s[2][4] = {};                                                       \
    __builtin_amdgcn_s_setprio(1);                                            \
    _Pragma("unroll")                                                         \
    for (int c = 0; c < 4; ++c) {                                             \
      const int krow = 32 * (c >> 1) + 8 * (l16 >> 2) + 4 * (c & 1) + (l16 & 3); \
      _Pragma("unroll")                                                       \
      for (int kk = 0; kk < 4; ++kk) {                                        \
        short8 kf = *(const short8*)&Ks[CUR][krow * 128 +                     \
                                            (((kk * 4 + l4) ^ kswz) * 8)];    \
        s[0][c] = mfma16(kf, qf[0][kk], s[0][c]);                             \
        s[1][c] = mfma16(kf, qf[1][kk], s[1][c]);                             \
      }                                                                       \
    }                                                                         \
    __builtin_amdgcn_s_setprio(0);                                            \
    float lmax[2];                                                            \
    _Pragma("unroll")                                                         \
    for (int qg = 0; qg < 2; ++qg) {                                          \
      float a = fmaxf(fmaxf(s[qg][0][0], s[qg][0][1]),                        \
                      fmaxf(s[qg][0][2], s[qg][0][3]));                       \
      _Pragma("unroll")                                                       \
      for (int c = 1; c < 4; ++c)                                             \
        a = fmaxf(a, fmaxf(fmaxf(s[qg][c][0], s[qg][c][1]),                   \
                           fmaxf(s[qg][c][2], s[qg][c][3])));                 \
      lmax[qg] = a;                                                           \
    }                                                                         \
    bool ok = (lmax[0] - mreg[0] <= 8.0f) && (lmax[1] - mreg[1] <= 8.0f);     \
    if (!__all(ok)) {                                                         \
      _Pragma("unroll")                                                       \
      for (int qg = 0; qg < 2; ++qg) {                                        \
        float a = fmaxf(lmax[qg], __shfl_xor(lmax[qg], 16));                  \
        float tmax = fmaxf(a, __shfl_xor(a, 32));                             \
        float mn = fmaxf(mreg[qg], tmax);                                     \
        float alpha = __builtin_amdgcn_exp2f(mreg[qg] - mn);                  \
        mreg[qg] = mn;                                                        \
        float af[4];                                                          \
        _Pragma("unroll")                                                     \
        for (int r = 0; r < 4; ++r)                                           \
          af[r] = __shfl(alpha, (lane & 48) + l4 * 4 + r);                    \
        _Pragma("unroll")                                                     \
        for (int g = 0; g < 8; ++g)                                           \
          _Pragma("unroll")                                                   \
          for (int r = 0; r < 4; ++r) o[qg][g][r] *= af[r];                   \
        _Pragma("unroll")                                                     \
        for (int r = 0; r < 4; ++r) ol[qg][r] *= af[r];                       \
      }                                                                       \
    }                                                                         \
    short8 pa[2];                                                             \
    _Pragma("unroll")                                                         \
    for (int ks = 0; ks < 2; ++ks) {                                          \
      _Pragma("unroll")                                                       \
      for (int qg = 0; qg < 2; ++qg) {                                        \
        short8 pk;                                                            \
        _Pragma("unroll")                                                     \
        for (int jj = 0; jj < 8; ++jj) {                                      \
          float p = __builtin_amdgcn_exp2f(                                   \
              s[qg][2 * ks + (jj >> 2)][jj & 3] - mreg[qg]);                  \
          pk[jj] = (short)f2bf(p);                                            \
        }                                                                     \
        pa[qg] = pk;                                                          \
      }                                                                       \
      __builtin_amdgcn_s_setprio(1);                                          \
      _Pragma("unroll")                                                       \
      for (int g = 0; g < 8; ++g) {                                           \
        const int d = g * 16 + l16;                                           \
        short8 vf = *(const short8*)&Vs[CUR][d * 64 +                         \
                                            (((ks * 4 + l4) ^ vswz) * 8)];    \
        o[0][g] = mfma16(pa[0], vf, o[0][g]);                                 \
        o[1][g] = mfma16(pa[1], vf, o[1][g]);                                 \
      }                                                                       \
      ol[0] = mfma16(pa[0], onesf, ol[0]);                                    \
      ol[1] = mfma16(pa[1], onesf, ol[1]);                                    \
      __builtin_amdgcn_s_setprio(0);                                          \
    }                                                                         \
    __builtin_amdgcn_s_barrier();                                             \
    __builtin_amdgcn_sched_barrier(0);                                        \
    if ((T) + 2 < NT) {                                                       \
      stage((T) + 2, CUR);                                                    \
      vmwait<8>();                                                            \
    } else if ((T) + 1 < NT) {                                                \
      vmwait<0>();                                                            \
    }                                                                         \
    if ((T) + 1 < NT) {                                                       \
      __builtin_amdgcn_s_barrier();                                           \
      __builtin_amdgcn_sched_barrier(0);                                      \
    }                                                                         \
  }

  for (int t = 0; t < NT; t += 2) {     // NT even; cur is a literal
    FBODY(0, t)
    FBODY(1, t + 1)
  }
#undef FBODY

  // epilogue: O rows are q = qg*16 + l4*4 + r; 1/l available in-lane via ol
#pragma unroll
  for (int qg = 0; qg < 2; ++qg) {
    float invq[4];
#pragma unroll
    for (int r = 0; r < 4; ++r) invq[r] = 1.0f / ol[qg][r];
    ushort* op = Oa + (size_t)(b * S_ + q0 + qg * 16) * D_ + h * DH_;
#pragma unroll
    for (int g = 0; g < 8; ++g)
#pragma unroll
      for (int r = 0; r < 4; ++r)
        op[(size_t)(l4 * 4 + r) * D_ + g * 16 + l16] = f2bf(o[qg][g][r] * invq[r]);
  }
}

// ---------------------------------------------------------------------------
extern "C" void kernel_launch(void* const* d_in, const int* in_sizes, int n_in,
                              void* d_out, int out_size, void* d_ws, size_t ws_size,
                              hipStream_t stream) {
  (void)in_sizes; (void)n_in; (void)out_size; (void)ws_size;
  const float* x  = (const float*)d_in[0];
  const float* Wq = (const float*)d_in[1];
  const float* Wk = (const float*)d_in[2];
  const float* Wv = (const float*)d_in[3];
  const float* Wo = (const float*)d_in[4];
  float* out = (float*)d_out;

  size_t off = 0;
  auto carve = [&](size_t bytes) -> void* {
    void* p = (char*)d_ws + off;
    off += (bytes + 255) & ~(size_t)255;
    return p;
  };
  ushort* xb    = (ushort*)carve((size_t)M_ * D_ * 2);
  ushort* Wqkvt = (ushort*)carve((size_t)NQKV * D_ * 2);   // [3072][2048]
  ushort* Wot   = (ushort*)carve((size_t)D_ * D_ * 2);
  ushort* QKV   = (ushort*)carve((size_t)M_ * NQKV * 2);   // [4096][3072]
  ushort* Vt    = (ushort*)carve((size_t)M_ * 512 * 2);
  ushort* attn  = (ushort*)carve((size_t)M_ * D_ * 2);
  float2* tab   = (float2*)carve((size_t)S_ * 64 * sizeof(float2));

  // 1. prep: x cast + rope table + all weight transposes (one launch)
  prep<<<18944, 256, 0, stream>>>(x, Wq, Wk, Wv, Wo, xb, Wqkvt, Wot, tab);

  // 2. fused QKV projection: [4096,2048] x [3072,2048]^T -> [4096,3072]
  gemm4p<192, 6, ushort><<<dim3(16, 16), 512, 0, stream>>>(xb, Wqkvt, QKV, M_, NQKV, 2048);

  // 3. RoPE Q+K (vec2, exp2-domain Q scale) + V transpose, one launch
  const float qscale = 0.08838834764831845f * 1.4426950408889634f;
  postqkv<<<12288, 256, 0, stream>>>(QKV, tab, qscale, Vt);

  // 4. attention
  flash_attn<<<dim3(16, 32), 256, 0, stream>>>(QKV, QKV + 2048, Vt, attn);

  // 5. output projection (f32 out)
  gemm4p<128, 4, float><<<dim3(16, 16), 512, 0, stream>>>(attn, Wot, out, M_, 2048, 2048);
}